// Round 19
// baseline (694.121 us; speedup 1.0000x reference)
//
#include <hip/hip_runtime.h>
#include <math.h>

#define T_LEN 1024
#define B_SZ  256
#define I_SZ  128
#define H_SZ  64
#define G_SZ  256   // 4*H
#define SUB   32    // recurrence steps per LDS-staged XG sub-chunk

typedef float f32x8 __attribute__((ext_vector_type(8)));
typedef float f32x2 __attribute__((ext_vector_type(2)));

__device__ __forceinline__ float fast_tanh(float x) {   // safe for any |x|
    float e = __expf(-2.0f * fabsf(x));
    float r = (1.0f - e) * __builtin_amdgcn_rcpf(1.0f + e);
    return copysignf(r, x);
}

#define LD8PIN(V, P)                                                        \
    {   float4 t0_ = *reinterpret_cast<const float4*>(P);                   \
        float4 t1_ = *reinterpret_cast<const float4*>((P) + 4);             \
        V = (f32x8){t0_.x, t0_.y, t0_.z, t0_.w, t1_.x, t1_.y, t1_.z, t1_.w};\
        asm volatile("" : "+v"(V)); }

// acc(4 chains) += h[K..K+15]*{VA,VB}; h via v_readlane with LITERAL indices
// (R12 lesson: divergent lane index = UB). 16 readlanes hoisted before FMAs.
#define RL16(VA, VB, K)                                                     \
    {   unsigned s0_  = __builtin_amdgcn_readlane(hu, (K) + 0);             \
        unsigned s1_  = __builtin_amdgcn_readlane(hu, (K) + 1);             \
        unsigned s2_  = __builtin_amdgcn_readlane(hu, (K) + 2);             \
        unsigned s3_  = __builtin_amdgcn_readlane(hu, (K) + 3);             \
        unsigned s4_  = __builtin_amdgcn_readlane(hu, (K) + 4);             \
        unsigned s5_  = __builtin_amdgcn_readlane(hu, (K) + 5);             \
        unsigned s6_  = __builtin_amdgcn_readlane(hu, (K) + 6);             \
        unsigned s7_  = __builtin_amdgcn_readlane(hu, (K) + 7);             \
        unsigned s8_  = __builtin_amdgcn_readlane(hu, (K) + 8);             \
        unsigned s9_  = __builtin_amdgcn_readlane(hu, (K) + 9);             \
        unsigned s10_ = __builtin_amdgcn_readlane(hu, (K) + 10);            \
        unsigned s11_ = __builtin_amdgcn_readlane(hu, (K) + 11);            \
        unsigned s12_ = __builtin_amdgcn_readlane(hu, (K) + 12);            \
        unsigned s13_ = __builtin_amdgcn_readlane(hu, (K) + 13);            \
        unsigned s14_ = __builtin_amdgcn_readlane(hu, (K) + 14);            \
        unsigned s15_ = __builtin_amdgcn_readlane(hu, (K) + 15);            \
        a0 = fmaf(__uint_as_float(s0_),  VA[0], a0);                        \
        a1 = fmaf(__uint_as_float(s1_),  VA[1], a1);                        \
        a2 = fmaf(__uint_as_float(s2_),  VA[2], a2);                        \
        a3 = fmaf(__uint_as_float(s3_),  VA[3], a3);                        \
        a0 = fmaf(__uint_as_float(s4_),  VA[4], a0);                        \
        a1 = fmaf(__uint_as_float(s5_),  VA[5], a1);                        \
        a2 = fmaf(__uint_as_float(s6_),  VA[6], a2);                        \
        a3 = fmaf(__uint_as_float(s7_),  VA[7], a3);                        \
        a0 = fmaf(__uint_as_float(s8_),  VB[0], a0);                        \
        a1 = fmaf(__uint_as_float(s9_),  VB[1], a1);                        \
        a2 = fmaf(__uint_as_float(s10_), VB[2], a2);                        \
        a3 = fmaf(__uint_as_float(s11_), VB[3], a3);                        \
        a0 = fmaf(__uint_as_float(s12_), VB[4], a0);                        \
        a1 = fmaf(__uint_as_float(s13_), VB[5], a1);                        \
        a2 = fmaf(__uint_as_float(s14_), VB[6], a2);                        \
        a3 = fmaf(__uint_as_float(s15_), VB[7], a3); }

// LDS column swizzle for the GEMM tiles
__device__ __forceinline__ int swz(int c) { return c + 4 * (c >> 5); }

#define GLOAD(K0)                                                           \
    { _Pragma("unroll") for (int i_ = 0; i_ < 4; ++i_) {                    \
        const int mr_ = srow + 32 * i_;                                     \
        pa[i_] = *reinterpret_cast<const float4*>(                          \
            &xch[(size_t)(mt * 128 + mr_) * I_SZ + (K0) + skk]);            \
        pb[i_] = *reinterpret_cast<const float4*>(                          \
            &W_ih[(size_t)(nt * 128 + mr_) * I_SZ + (K0) + skk]); } }

#define SWRITE(BUF)                                                         \
    { _Pragma("unroll") for (int i_ = 0; i_ < 4; ++i_) {                    \
        const int mr_ = srow + 32 * i_; const int sm_ = swz(mr_);           \
        as[BUF][skk + 0][sm_] = pa[i_].x; as[BUF][skk + 1][sm_] = pa[i_].y; \
        as[BUF][skk + 2][sm_] = pa[i_].z; as[BUF][skk + 3][sm_] = pa[i_].w; \
        bs[BUF][skk + 0][sm_] = pb[i_].x; bs[BUF][skk + 1][sm_] = pb[i_].y; \
        bs[BUF][skk + 2][sm_] = pb[i_].z; bs[BUF][skk + 3][sm_] = pb[i_].w; } }

// ---------------------------------------------------------------------------
// Combined kernel: blocks [0, nrec) run the R15 recurrence for chunk i
// (reads XGin); blocks [nrec, nrec+2*MT) run the R18 GEMM for chunk i+1
// (writes XGout). No intra-kernel dependency — stream order between launches
// provides chunk i's XG. A rec block (4 waves, latency-bound, 12% occupancy)
// and a gemm block (DS/VALU-heavy) co-reside per CU: gemm fills rec stalls.
// Worst case (dispatcher serializes roles) == previous serial pipeline.
// ---------------------------------------------------------------------------
__global__ __launch_bounds__(256, 1) void rec_gemm(
    // rec args (chunk i)
    const float* __restrict__ XGin,   // [TC,B,256]
    const float* __restrict__ W_hh,   // [256,64]
    float* __restrict__ h_state,      // [B,64]
    float* __restrict__ c_state,      // [B,64]
    int TC, int first, int nrec,
    // gemm args (chunk i+1)
    const float* __restrict__ xch,    // [TC*B,128]
    const float* __restrict__ W_ih,   // [256,128]
    const float* __restrict__ bias,   // [256]
    float* __restrict__ XGout,        // [TC*B,256]
    int MT)                           // m-tiles (TC*B/128)
{
    __shared__ __align__(16) float smem[17920];   // 71.7 KB (union rec/gemm)

    if ((int)blockIdx.x < nrec) {
        // ================= REC path (R15 verbatim, smem-cast) =============
        float (*xgl)[SUB][G_SZ] = reinterpret_cast<float(*)[SUB][G_SZ]>(smem);
        float (*gs)[G_SZ]       = reinterpret_cast<float(*)[G_SZ]>(smem + 16384);

        const int b = blockIdx.x;
        const int t = threadIdx.x;
        const int l = t & 63;
        const int g = t >> 6;
        const int row = t;

        const float* ur = W_hh + row * H_SZ;
        f32x8 w0, w1, w2, w3, w4, w5, w6, w7;
        LD8PIN(w0, ur)      LD8PIN(w1, ur +  8) LD8PIN(w2, ur + 16) LD8PIN(w3, ur + 24)
        LD8PIN(w4, ur + 32) LD8PIN(w5, ur + 40) LD8PIN(w6, ur + 48) LD8PIN(w7, ur + 56)

        float h = first ? 0.0f : h_state[b * H_SZ + l];
        float c = first ? 0.0f : c_state[b * H_SZ + l];

        {
            float* xf = &xgl[0][0][0];
#pragma unroll
            for (int i = 0; i < 8; ++i) {
                const int F = t + 256 * i;
                const int r = F >> 6, cw = F & 63;
                *reinterpret_cast<float4*>(xf + 4 * F) =
                    *reinterpret_cast<const float4*>(
                        XGin + ((size_t)r * B_SZ + b) * G_SZ + 4 * cw);
            }
        }
        __syncthreads();

        const bool isg = (g == 2);
        const int nsub = TC / SUB;
        int db = 0;

        for (int sub = 0; sub < nsub; ++sub) {
            const int cur = sub & 1;
            if (sub + 1 < nsub) {
                float* xf = &xgl[cur ^ 1][0][0];
#pragma unroll
                for (int i = 0; i < 8; ++i) {
                    const int F = t + 256 * i;
                    const int r = (F >> 6) + (sub + 1) * SUB, cw = F & 63;
                    *reinterpret_cast<float4*>(xf + 4 * F) =
                        *reinterpret_cast<const float4*>(
                            XGin + ((size_t)r * B_SZ + b) * G_SZ + 4 * cw);
                }
            }

#pragma unroll 4
            for (int ts = 0; ts < SUB; ++ts) {
                const unsigned hu = __float_as_uint(h);
                float a0 = xgl[cur][ts][row];
                float a1 = 0.0f, a2 = 0.0f, a3 = 0.0f;
                RL16(w0, w1,  0) RL16(w2, w3, 16)
                RL16(w4, w5, 32) RL16(w6, w7, 48)
                const float acc = (a0 + a1) + (a2 + a3);

                const float arg = isg ? (-2.0f * acc) : (-acc);
                const float e = __expf(arg);
                const float r = __builtin_amdgcn_rcpf(1.0f + e);
                const float a = isg ? (1.0f - e) * r : r;

                gs[db][row] = a;
                __syncthreads();

                const float ig = gs[db][l];
                const float fg = gs[db][H_SZ + l];
                const float gg = gs[db][2 * H_SZ + l];
                const float og = gs[db][3 * H_SZ + l];
                c = fmaf(fg, c, ig * gg);
                h = og * fast_tanh(c);
                db ^= 1;
            }
        }

        if (t < H_SZ) {
            h_state[b * H_SZ + t] = h;
            c_state[b * H_SZ + t] = c;
        }
    } else {
        // ================= GEMM path (R18 verbatim, smem-cast) ============
        float (*as)[32][140] = reinterpret_cast<float(*)[32][140]>(smem);
        float (*bs)[32][140] = reinterpret_cast<float(*)[32][140]>(smem + 8960);

        const int gb  = blockIdx.x - nrec;
        const int mt  = gb % MT;
        const int nt  = gb / MT;
        const int tid = threadIdx.x;
        const int tx  = tid & 15;
        const int ty  = tid >> 4;

        const int n0 = nt * 128 + tx * 8;
        float4 bia = *reinterpret_cast<const float4*>(&bias[n0]);
        float4 bib = *reinterpret_cast<const float4*>(&bias[n0 + 4]);

        f32x2 acc2[8][4];
#pragma unroll
        for (int r = 0; r < 8; ++r)
#pragma unroll
            for (int cc = 0; cc < 4; ++cc) acc2[r][cc] = (f32x2){0.0f, 0.0f};

        const int srow = tid >> 3;
        const int skk  = (tid & 7) * 4;

        float4 pa[4], pb[4];
        GLOAD(0) SWRITE(0)
        __syncthreads();

#pragma unroll
        for (int ks = 0; ks < 4; ++ks) {
            if (ks < 3) GLOAD((ks + 1) * 32)

            const int buf = ks & 1;
#pragma unroll 8
            for (int kk = 0; kk < 32; ++kk) {
                const float4 a0 = *reinterpret_cast<const float4*>(&as[buf][kk][swz(ty * 8)]);
                const float4 a1 = *reinterpret_cast<const float4*>(&as[buf][kk][swz(ty * 8) + 4]);
                const float4 b0 = *reinterpret_cast<const float4*>(&bs[buf][kk][swz(tx * 8)]);
                const float4 b1 = *reinterpret_cast<const float4*>(&bs[buf][kk][swz(tx * 8) + 4]);
                const float av[8] = {a0.x, a0.y, a0.z, a0.w, a1.x, a1.y, a1.z, a1.w};
                const f32x2 bv2[4] = {{b0.x, b0.y}, {b0.z, b0.w},
                                      {b1.x, b1.y}, {b1.z, b1.w}};
#pragma unroll
                for (int r = 0; r < 8; ++r) {
                    const f32x2 a2 = {av[r], av[r]};
#pragma unroll
                    for (int cc = 0; cc < 4; ++cc)
                        acc2[r][cc] = a2 * bv2[cc] + acc2[r][cc];
                }
            }

            if (ks < 3) {
                SWRITE(buf ^ 1)
                __syncthreads();
            }
        }

#pragma unroll
        for (int r = 0; r < 8; ++r) {
            const size_t m = (size_t)(mt * 128 + ty * 8 + r);
            float4 o0 = {acc2[r][0].x + bia.x, acc2[r][0].y + bia.y,
                         acc2[r][1].x + bia.z, acc2[r][1].y + bia.w};
            float4 o1 = {acc2[r][2].x + bib.x, acc2[r][2].y + bib.y,
                         acc2[r][3].x + bib.z, acc2[r][3].y + bib.w};
            *reinterpret_cast<float4*>(&XGout[m * G_SZ + n0])     = o0;
            *reinterpret_cast<float4*>(&XGout[m * G_SZ + n0 + 4]) = o1;
        }
    }
}

// ---------------------------------------------------------------------------
// Reverse single cell (zero init state; W_hh_r drops out) + MLP head.
// ---------------------------------------------------------------------------
__global__ __launch_bounds__(256, 1) void lstm_tail(
    const float* __restrict__ x_last,  // [B,I]
    const float* __restrict__ W_ih_r,  // [256,128]
    const float* __restrict__ b_r,     // [256]
    const float* __restrict__ h_fwd,   // [B,64]
    const float* __restrict__ fc1_w,   // [64,128]
    const float* __restrict__ fc1_b,   // [64]
    const float* __restrict__ fc2_w,   // [32,64]
    const float* __restrict__ fc2_b,   // [32]
    const float* __restrict__ fc3_w,   // [10,32]
    const float* __restrict__ fc3_b,   // [10]
    float* __restrict__ out)           // [B,10]
{
    const int b = blockIdx.x;
    const int j = threadIdx.x;

    __shared__ float xs[I_SZ];
    __shared__ float gs[G_SZ];
    __shared__ float hc[2 * H_SZ];
    __shared__ float h1[64];
    __shared__ float h2[32];

    if (j < I_SZ) xs[j] = x_last[(size_t)b * I_SZ + j];
    if (j < H_SZ) hc[j] = h_fwd[b * H_SZ + j];
    __syncthreads();

    float a0 = b_r[j], a1 = 0.0f, a2 = 0.0f, a3 = 0.0f;
    const float* wrow = W_ih_r + j * I_SZ;
#pragma unroll
    for (int kk = 0; kk < I_SZ; kk += 4) {
        float4 wv = *reinterpret_cast<const float4*>(wrow + kk);
        a0 = fmaf(xs[kk + 0], wv.x, a0);
        a1 = fmaf(xs[kk + 1], wv.y, a1);
        a2 = fmaf(xs[kk + 2], wv.z, a2);
        a3 = fmaf(xs[kk + 3], wv.w, a3);
    }
    const float acc = (a0 + a1) + (a2 + a3);
    const int gate = j >> 6;
    gs[j] = (gate == 2) ? tanhf(acc) : 1.0f / (1.0f + expf(-acc));
    __syncthreads();

    if (j < H_SZ) {
        const float cc = gs[j] * gs[2 * H_SZ + j];     // i*g (c0 = 0)
        hc[H_SZ + j] = gs[3 * H_SZ + j] * tanhf(cc);
    }
    __syncthreads();

    if (j < 64) {
        float s0 = fc1_b[j], s1 = 0.0f, s2 = 0.0f, s3 = 0.0f;
        const float* w = fc1_w + j * 128;
#pragma unroll
        for (int kk = 0; kk < 128; kk += 4) {
            float4 wv = *reinterpret_cast<const float4*>(w + kk);
            s0 = fmaf(hc[kk + 0], wv.x, s0);
            s1 = fmaf(hc[kk + 1], wv.y, s1);
            s2 = fmaf(hc[kk + 2], wv.z, s2);
            s3 = fmaf(hc[kk + 3], wv.w, s3);
        }
        h1[j] = fmaxf((s0 + s1) + (s2 + s3), 0.0f);
    }
    __syncthreads();

    if (j < 32) {
        float s0 = fc2_b[j], s1 = 0.0f, s2 = 0.0f, s3 = 0.0f;
        const float* w = fc2_w + j * 64;
#pragma unroll
        for (int kk = 0; kk < 64; kk += 4) {
            float4 wv = *reinterpret_cast<const float4*>(w + kk);
            s0 = fmaf(h1[kk + 0], wv.x, s0);
            s1 = fmaf(h1[kk + 1], wv.y, s1);
            s2 = fmaf(h1[kk + 2], wv.z, s2);
            s3 = fmaf(h1[kk + 3], wv.w, s3);
        }
        h2[j] = fmaxf((s0 + s1) + (s2 + s3), 0.0f);
    }
    __syncthreads();

    if (j < 10) {
        float s = fc3_b[j];
#pragma unroll
        for (int kk = 0; kk < 32; ++kk) s = fmaf(h2[kk], fc3_w[j * 32 + kk], s);
        out[b * 10 + j] = s;
    }
}

extern "C" void kernel_launch(void* const* d_in, const int* in_sizes, int n_in,
                              void* d_out, int out_size, void* d_ws, size_t ws_size,
                              hipStream_t stream) {
    const float* x      = (const float*)d_in[0];
    const float* W_ih_f = (const float*)d_in[1];
    const float* W_hh_f = (const float*)d_in[2];
    const float* b_f    = (const float*)d_in[3];
    const float* W_ih_r = (const float*)d_in[4];
    // d_in[5] = W_hh_r : unused (zero initial state in reverse single step)
    const float* b_r    = (const float*)d_in[6];
    const float* fc1_w  = (const float*)d_in[7];
    const float* fc1_b  = (const float*)d_in[8];
    const float* fc2_w  = (const float*)d_in[9];
    const float* fc2_b  = (const float*)d_in[10];
    const float* fc3_w  = (const float*)d_in[11];
    const float* fc3_b  = (const float*)d_in[12];
    float* out = (float*)d_out;

    // chunk size: need TWO XG buffers (double buffer) + state in ws.
    // Cap at 256 for overlap granularity (4 chunks).
    int TC = 256;
    while (TC > 64 &&
           2 * (size_t)TC * B_SZ * G_SZ * 4 + 2 * B_SZ * H_SZ * 4 > ws_size)
        TC >>= 1;

    const size_t xg_elems = (size_t)TC * B_SZ * G_SZ;
    float* XGbuf[2];
    XGbuf[0] = (float*)d_ws;
    XGbuf[1] = XGbuf[0] + xg_elems;
    float* h_state = XGbuf[1] + xg_elems;
    float* c_state = h_state + B_SZ * H_SZ;

    const int NCH = T_LEN / TC;
    const int MT  = TC * B_SZ / 128;       // m-tiles per chunk

    // launch 0: gemm-only for chunk 0 -> buf0
    hipLaunchKernelGGL(rec_gemm, dim3(2 * MT), dim3(256), 0, stream,
                       XGbuf[0], W_hh_f, h_state, c_state, TC, 1, /*nrec=*/0,
                       x, W_ih_f, b_f, XGbuf[0], MT);

    for (int ch = 0; ch < NCH; ++ch) {
        const bool hasg = (ch + 1 < NCH);
        const float* xnext = hasg ? x + (size_t)(ch + 1) * TC * B_SZ * I_SZ : x;
        float* XGout = XGbuf[(ch + 1) & 1];
        const int grid = B_SZ + (hasg ? 2 * MT : 0);
        hipLaunchKernelGGL(rec_gemm, dim3(grid), dim3(256), 0, stream,
                           XGbuf[ch & 1], W_hh_f, h_state, c_state,
                           TC, ch == 0 ? 1 : 0, /*nrec=*/B_SZ,
                           xnext, W_ih_f, b_f, XGout, MT);
    }

    const float* x_last = x + (size_t)(T_LEN - 1) * B_SZ * I_SZ;
    hipLaunchKernelGGL(lstm_tail, dim3(B_SZ), dim3(256), 0, stream,
                       x_last, W_ih_r, b_r, h_state,
                       fc1_w, fc1_b, fc2_w, fc2_b, fc3_w, fc3_b, out);
}

// Round 20
// 616.292 us; speedup vs baseline: 1.1263x; 1.1263x over previous
//
#include <hip/hip_runtime.h>
#include <math.h>

#define T_LEN 1024
#define B_SZ  256
#define I_SZ  128
#define H_SZ  64
#define G_SZ  256   // 4*H
#define SUB   32    // recurrence steps per LDS-staged XG sub-chunk

typedef float f32x8 __attribute__((ext_vector_type(8)));
typedef float f32x2 __attribute__((ext_vector_type(2)));

__device__ __forceinline__ float fast_tanh(float x) {   // safe for any |x|
    float e = __expf(-2.0f * fabsf(x));
    float r = (1.0f - e) * __builtin_amdgcn_rcpf(1.0f + e);
    return copysignf(r, x);
}

#define LD8PIN(V, P)                                                        \
    {   float4 t0_ = *reinterpret_cast<const float4*>(P);                   \
        float4 t1_ = *reinterpret_cast<const float4*>((P) + 4);             \
        V = (f32x8){t0_.x, t0_.y, t0_.z, t0_.w, t1_.x, t1_.y, t1_.z, t1_.w};\
        asm volatile("" : "+v"(V)); }

// acc(4 chains) += h[K..K+15]*{VA,VB}; h via v_readlane with LITERAL indices
// (R12 lesson: divergent lane index = UB). 16 readlanes hoisted before FMAs.
#define RL16(VA, VB, K)                                                     \
    {   unsigned s0_  = __builtin_amdgcn_readlane(hu, (K) + 0);             \
        unsigned s1_  = __builtin_amdgcn_readlane(hu, (K) + 1);             \
        unsigned s2_  = __builtin_amdgcn_readlane(hu, (K) + 2);             \
        unsigned s3_  = __builtin_amdgcn_readlane(hu, (K) + 3);             \
        unsigned s4_  = __builtin_amdgcn_readlane(hu, (K) + 4);             \
        unsigned s5_  = __builtin_amdgcn_readlane(hu, (K) + 5);             \
        unsigned s6_  = __builtin_amdgcn_readlane(hu, (K) + 6);             \
        unsigned s7_  = __builtin_amdgcn_readlane(hu, (K) + 7);             \
        unsigned s8_  = __builtin_amdgcn_readlane(hu, (K) + 8);             \
        unsigned s9_  = __builtin_amdgcn_readlane(hu, (K) + 9);             \
        unsigned s10_ = __builtin_amdgcn_readlane(hu, (K) + 10);            \
        unsigned s11_ = __builtin_amdgcn_readlane(hu, (K) + 11);            \
        unsigned s12_ = __builtin_amdgcn_readlane(hu, (K) + 12);            \
        unsigned s13_ = __builtin_amdgcn_readlane(hu, (K) + 13);            \
        unsigned s14_ = __builtin_amdgcn_readlane(hu, (K) + 14);            \
        unsigned s15_ = __builtin_amdgcn_readlane(hu, (K) + 15);            \
        a0 = fmaf(__uint_as_float(s0_),  VA[0], a0);                        \
        a1 = fmaf(__uint_as_float(s1_),  VA[1], a1);                        \
        a2 = fmaf(__uint_as_float(s2_),  VA[2], a2);                        \
        a3 = fmaf(__uint_as_float(s3_),  VA[3], a3);                        \
        a0 = fmaf(__uint_as_float(s4_),  VA[4], a0);                        \
        a1 = fmaf(__uint_as_float(s5_),  VA[5], a1);                        \
        a2 = fmaf(__uint_as_float(s6_),  VA[6], a2);                        \
        a3 = fmaf(__uint_as_float(s7_),  VA[7], a3);                        \
        a0 = fmaf(__uint_as_float(s8_),  VB[0], a0);                        \
        a1 = fmaf(__uint_as_float(s9_),  VB[1], a1);                        \
        a2 = fmaf(__uint_as_float(s10_), VB[2], a2);                        \
        a3 = fmaf(__uint_as_float(s11_), VB[3], a3);                        \
        a0 = fmaf(__uint_as_float(s12_), VB[4], a0);                        \
        a1 = fmaf(__uint_as_float(s13_), VB[5], a1);                        \
        a2 = fmaf(__uint_as_float(s14_), VB[6], a2);                        \
        a3 = fmaf(__uint_as_float(s15_), VB[7], a3); }

// LDS column swizzle for the GEMM tiles
__device__ __forceinline__ int swz(int c) { return c + 4 * (c >> 5); }

// GEMM staging: global -> regs (issued early, latency hidden under compute)
#define GLOAD(K0)                                                           \
    { _Pragma("unroll") for (int i_ = 0; i_ < 4; ++i_) {                    \
        const int mr_ = srow + 32 * i_;                                     \
        pa[i_] = *reinterpret_cast<const float4*>(                          \
            &xch[(size_t)(mt * 128 + mr_) * I_SZ + (K0) + skk]);            \
        pb[i_] = *reinterpret_cast<const float4*>(                          \
            &W_ih[(size_t)(nt * 128 + mr_) * I_SZ + (K0) + skk]); } }

// GEMM staging: regs -> LDS (after compute; one barrier per stage)
#define SWRITE(BUF)                                                         \
    { _Pragma("unroll") for (int i_ = 0; i_ < 4; ++i_) {                    \
        const int mr_ = srow + 32 * i_; const int sm_ = swz(mr_);           \
        as[BUF][skk + 0][sm_] = pa[i_].x; as[BUF][skk + 1][sm_] = pa[i_].y; \
        as[BUF][skk + 2][sm_] = pa[i_].z; as[BUF][skk + 3][sm_] = pa[i_].w; \
        bs[BUF][skk + 0][sm_] = pb[i_].x; bs[BUF][skk + 1][sm_] = pb[i_].y; \
        bs[BUF][skk + 2][sm_] = pb[i_].z; bs[BUF][skk + 3][sm_] = pb[i_].w; } }

// ---------------------------------------------------------------------------
// XG GEMM, double-buffered + f32x2 packed accumulate (R18-proven, ~190us).
// ---------------------------------------------------------------------------
__global__ __launch_bounds__(256, 2) void xg_gemm(
    const float* __restrict__ xch,    // [Mc,128] chunk of x
    const float* __restrict__ W_ih,   // [256,128]
    const float* __restrict__ bias,   // [256]
    float* __restrict__ XG)           // [Mc,256]
{
    const int tid = threadIdx.x;
    const int tx  = tid & 15;
    const int ty  = tid >> 4;
    const int mt  = blockIdx.x;
    const int nt  = blockIdx.y;

    __shared__ __align__(16) float as[2][32][140];   // 35.8 KB
    __shared__ __align__(16) float bs[2][32][140];   // 35.8 KB

    const int n0 = nt * 128 + tx * 8;
    float4 bia = *reinterpret_cast<const float4*>(&bias[n0]);
    float4 bib = *reinterpret_cast<const float4*>(&bias[n0 + 4]);

    f32x2 acc2[8][4];
#pragma unroll
    for (int r = 0; r < 8; ++r)
#pragma unroll
        for (int cc = 0; cc < 4; ++cc) acc2[r][cc] = (f32x2){0.0f, 0.0f};

    const int srow = tid >> 3;            // 0..31
    const int skk  = (tid & 7) * 4;       // 0,4,..,28

    float4 pa[4], pb[4];
    GLOAD(0) SWRITE(0)
    __syncthreads();

#pragma unroll
    for (int ks = 0; ks < 4; ++ks) {
        if (ks < 3) GLOAD((ks + 1) * 32)  // prefetch next stage (in flight)

        const int buf = ks & 1;
#pragma unroll 8
        for (int kk = 0; kk < 32; ++kk) {
            const float4 a0 = *reinterpret_cast<const float4*>(&as[buf][kk][swz(ty * 8)]);
            const float4 a1 = *reinterpret_cast<const float4*>(&as[buf][kk][swz(ty * 8) + 4]);
            const float4 b0 = *reinterpret_cast<const float4*>(&bs[buf][kk][swz(tx * 8)]);
            const float4 b1 = *reinterpret_cast<const float4*>(&bs[buf][kk][swz(tx * 8) + 4]);
            const float av[8] = {a0.x, a0.y, a0.z, a0.w, a1.x, a1.y, a1.z, a1.w};
            const f32x2 bv2[4] = {{b0.x, b0.y}, {b0.z, b0.w},
                                  {b1.x, b1.y}, {b1.z, b1.w}};
#pragma unroll
            for (int r = 0; r < 8; ++r) {
                const f32x2 a2 = {av[r], av[r]};
#pragma unroll
                for (int cc = 0; cc < 4; ++cc)
                    acc2[r][cc] = a2 * bv2[cc] + acc2[r][cc];  // v_pk_fma_f32
            }
        }

        if (ks < 3) {
            SWRITE(buf ^ 1)               // prev readers of buf^1 done (bar ks-1)
            __syncthreads();              // one barrier per stage
        }
    }

#pragma unroll
    for (int r = 0; r < 8; ++r) {
        const size_t m = (size_t)(mt * 128 + ty * 8 + r);
        float4 o0 = {acc2[r][0].x + bia.x, acc2[r][0].y + bia.y,
                     acc2[r][1].x + bia.z, acc2[r][1].y + bia.w};
        float4 o1 = {acc2[r][2].x + bib.x, acc2[r][2].y + bib.y,
                     acc2[r][3].x + bib.z, acc2[r][3].y + bib.w};
        *reinterpret_cast<float4*>(&XG[m * G_SZ + n0])     = o0;
        *reinterpret_cast<float4*>(&XG[m * G_SZ + n0 + 4]) = o1;
    }
}

// ---------------------------------------------------------------------------
// Recurrence (R15 structure — proven 404us, absmax 1.9e-6, VGPR 88) with xg
// moved to a TAIL-ADD: the ds_read_b32 of xg no longer heads chain a0, so its
// ~120cyc latency hides fully under the 300cyc readlane/FMA stream.
// ---------------------------------------------------------------------------
__global__ __launch_bounds__(256, 1) void lstm_rec(
    const float* __restrict__ XG,     // [TC,B,256]
    const float* __restrict__ W_hh,   // [256,64]
    float* __restrict__ h_state,      // [B,64]
    float* __restrict__ c_state,      // [B,64]
    int TC, int first)
{
    const int b = blockIdx.x;
    const int t = threadIdx.x;
    const int l = t & 63;             // lane = unit (cell phase)
    const int g = t >> 6;             // wave = gate: 0=i 1=f 2=g 3=o
    const int row = t;                // gate row g*64+l

    __shared__ __align__(16) float xgl[2][SUB][G_SZ];   // 64 KB
    __shared__ float gs[2][G_SZ];                       // double-buffered gates

    // full W_hh row -> 64 pinned register floats (R8-proven resident)
    const float* ur = W_hh + row * H_SZ;
    f32x8 w0, w1, w2, w3, w4, w5, w6, w7;
    LD8PIN(w0, ur)      LD8PIN(w1, ur +  8) LD8PIN(w2, ur + 16) LD8PIN(w3, ur + 24)
    LD8PIN(w4, ur + 32) LD8PIN(w5, ur + 40) LD8PIN(w6, ur + 48) LD8PIN(w7, ur + 56)

    // replicated state in lane registers (every wave: lane l = unit l)
    float h = first ? 0.0f : h_state[b * H_SZ + l];
    float c = first ? 0.0f : c_state[b * H_SZ + l];

    // stage sub-chunk 0: flat coalesced copy (thread t copies f4 #t+256i)
    {
        float* xf = &xgl[0][0][0];
#pragma unroll
        for (int i = 0; i < 8; ++i) {
            const int F = t + 256 * i;            // float4 index 0..2047
            const int r = F >> 6, cw = F & 63;    // step row, float4 col
            *reinterpret_cast<float4*>(xf + 4 * F) =
                *reinterpret_cast<const float4*>(
                    XG + ((size_t)r * B_SZ + b) * G_SZ + 4 * cw);
        }
    }
    __syncthreads();

    const bool isg = (g == 2);        // wave-uniform
    const int nsub = TC / SUB;
    int db = 0;

    for (int sub = 0; sub < nsub; ++sub) {
        const int cur = sub & 1;
        if (sub + 1 < nsub) {         // stage next sub-chunk (flat copy)
            float* xf = &xgl[cur ^ 1][0][0];
#pragma unroll
            for (int i = 0; i < 8; ++i) {
                const int F = t + 256 * i;
                const int r = (F >> 6) + (sub + 1) * SUB, cw = F & 63;
                *reinterpret_cast<float4*>(xf + 4 * F) =
                    *reinterpret_cast<const float4*>(
                        XG + ((size_t)r * B_SZ + b) * G_SZ + 4 * cw);
            }
        }

#pragma unroll 4
        for (int ts = 0; ts < SUB; ++ts) {
            // xg load issues here; consumed only AFTER the dot (latency hidden)
            const float xg = xgl[cur][ts][row];   // banks 0..31, conflict-free

            // h-dot: 64 readlane + 64 FMA (VALU only), hoisted by 16s
            const unsigned hu = __float_as_uint(h);
            float a0 = 0.0f, a1 = 0.0f, a2 = 0.0f, a3 = 0.0f;
            RL16(w0, w1,  0) RL16(w2, w3, 16)
            RL16(w4, w5, 32) RL16(w6, w7, 48)
            const float acc = ((a0 + a1) + (a2 + a3)) + xg;   // tail-add

            // activation (wave-uniform gate; branchless select)
            const float arg = isg ? (-2.0f * acc) : (-acc);
            const float e = __expf(arg);
            const float r = __builtin_amdgcn_rcpf(1.0f + e);
            const float a = isg ? (1.0f - e) * r : r;

            gs[db][row] = a;                      // banks 0..31, conflict-free
            __syncthreads();                      // gates visible

            // replicated cell update: lane l handles unit l (4 free b32 reads)
            const float ig = gs[db][l];
            const float fg = gs[db][H_SZ + l];
            const float gg = gs[db][2 * H_SZ + l];
            const float og = gs[db][3 * H_SZ + l];
            c = fmaf(fg, c, ig * gg);
            h = og * fast_tanh(c);                // stays in registers
            db ^= 1;
        }
    }

    if (t < H_SZ) {                               // wave 0 writes final state
        h_state[b * H_SZ + t] = h;
        c_state[b * H_SZ + t] = c;
    }
}

// ---------------------------------------------------------------------------
// Reverse single cell (zero init state; W_hh_r drops out) + MLP head.
// ---------------------------------------------------------------------------
__global__ __launch_bounds__(256, 1) void lstm_tail(
    const float* __restrict__ x_last,  // [B,I]
    const float* __restrict__ W_ih_r,  // [256,128]
    const float* __restrict__ b_r,     // [256]
    const float* __restrict__ h_fwd,   // [B,64]
    const float* __restrict__ fc1_w,   // [64,128]
    const float* __restrict__ fc1_b,   // [64]
    const float* __restrict__ fc2_w,   // [32,64]
    const float* __restrict__ fc2_b,   // [32]
    const float* __restrict__ fc3_w,   // [10,32]
    const float* __restrict__ fc3_b,   // [10]
    float* __restrict__ out)           // [B,10]
{
    const int b = blockIdx.x;
    const int j = threadIdx.x;

    __shared__ float xs[I_SZ];
    __shared__ float gs[G_SZ];
    __shared__ float hc[2 * H_SZ];
    __shared__ float h1[64];
    __shared__ float h2[32];

    if (j < I_SZ) xs[j] = x_last[(size_t)b * I_SZ + j];
    if (j < H_SZ) hc[j] = h_fwd[b * H_SZ + j];
    __syncthreads();

    float a0 = b_r[j], a1 = 0.0f, a2 = 0.0f, a3 = 0.0f;
    const float* wrow = W_ih_r + j * I_SZ;
#pragma unroll
    for (int kk = 0; kk < I_SZ; kk += 4) {
        float4 wv = *reinterpret_cast<const float4*>(wrow + kk);
        a0 = fmaf(xs[kk + 0], wv.x, a0);
        a1 = fmaf(xs[kk + 1], wv.y, a1);
        a2 = fmaf(xs[kk + 2], wv.z, a2);
        a3 = fmaf(xs[kk + 3], wv.w, a3);
    }
    const float acc = (a0 + a1) + (a2 + a3);
    const int gate = j >> 6;
    gs[j] = (gate == 2) ? tanhf(acc) : 1.0f / (1.0f + expf(-acc));
    __syncthreads();

    if (j < H_SZ) {
        const float cc = gs[j] * gs[2 * H_SZ + j];     // i*g (c0 = 0)
        hc[H_SZ + j] = gs[3 * H_SZ + j] * tanhf(cc);
    }
    __syncthreads();

    if (j < 64) {
        float s0 = fc1_b[j], s1 = 0.0f, s2 = 0.0f, s3 = 0.0f;
        const float* w = fc1_w + j * 128;
#pragma unroll
        for (int kk = 0; kk < 128; kk += 4) {
            float4 wv = *reinterpret_cast<const float4*>(w + kk);
            s0 = fmaf(hc[kk + 0], wv.x, s0);
            s1 = fmaf(hc[kk + 1], wv.y, s1);
            s2 = fmaf(hc[kk + 2], wv.z, s2);
            s3 = fmaf(hc[kk + 3], wv.w, s3);
        }
        h1[j] = fmaxf((s0 + s1) + (s2 + s3), 0.0f);
    }
    __syncthreads();

    if (j < 32) {
        float s0 = fc2_b[j], s1 = 0.0f, s2 = 0.0f, s3 = 0.0f;
        const float* w = fc2_w + j * 64;
#pragma unroll
        for (int kk = 0; kk < 64; kk += 4) {
            float4 wv = *reinterpret_cast<const float4*>(w + kk);
            s0 = fmaf(h1[kk + 0], wv.x, s0);
            s1 = fmaf(h1[kk + 1], wv.y, s1);
            s2 = fmaf(h1[kk + 2], wv.z, s2);
            s3 = fmaf(h1[kk + 3], wv.w, s3);
        }
        h2[j] = fmaxf((s0 + s1) + (s2 + s3), 0.0f);
    }
    __syncthreads();

    if (j < 10) {
        float s = fc3_b[j];
#pragma unroll
        for (int kk = 0; kk < 32; ++kk) s = fmaf(h2[kk], fc3_w[j * 32 + kk], s);
        out[b * 10 + j] = s;
    }
}

extern "C" void kernel_launch(void* const* d_in, const int* in_sizes, int n_in,
                              void* d_out, int out_size, void* d_ws, size_t ws_size,
                              hipStream_t stream) {
    const float* x      = (const float*)d_in[0];
    const float* W_ih_f = (const float*)d_in[1];
    const float* W_hh_f = (const float*)d_in[2];
    const float* b_f    = (const float*)d_in[3];
    const float* W_ih_r = (const float*)d_in[4];
    // d_in[5] = W_hh_r : unused (zero initial state in reverse single step)
    const float* b_r    = (const float*)d_in[6];
    const float* fc1_w  = (const float*)d_in[7];
    const float* fc1_b  = (const float*)d_in[8];
    const float* fc2_w  = (const float*)d_in[9];
    const float* fc2_b  = (const float*)d_in[10];
    const float* fc3_w  = (const float*)d_in[11];
    const float* fc3_b  = (const float*)d_in[12];
    float* out = (float*)d_out;

    // time-chunk size: largest TC whose XG buffer (+state) fits in ws
    int TC = 1024;
    while (TC > 64 &&
           (size_t)TC * B_SZ * G_SZ * 4 + 2 * B_SZ * H_SZ * 4 > ws_size)
        TC >>= 1;

    float* XG      = (float*)d_ws;
    float* h_state = (float*)((char*)d_ws + (size_t)TC * B_SZ * G_SZ * 4);
    float* c_state = h_state + B_SZ * H_SZ;

    const int NCH = T_LEN / TC;
    for (int ch = 0; ch < NCH; ++ch) {
        const float* xch = x + (size_t)ch * TC * B_SZ * I_SZ;
        hipLaunchKernelGGL(xg_gemm, dim3(TC * B_SZ / 128, 2), dim3(256), 0,
                           stream, xch, W_ih_f, b_f, XG);
        hipLaunchKernelGGL(lstm_rec, dim3(B_SZ), dim3(256), 0, stream,
                           XG, W_hh_f, h_state, c_state, TC, ch == 0 ? 1 : 0);
    }

    const float* x_last = x + (size_t)(T_LEN - 1) * B_SZ * I_SZ;
    hipLaunchKernelGGL(lstm_tail, dim3(B_SZ), dim3(256), 0, stream,
                       x_last, W_ih_r, b_r, h_state,
                       fc1_w, fc1_b, fc2_w, fc2_b, fc3_w, fc3_b, out);
}

// Round 21
// 606.789 us; speedup vs baseline: 1.1439x; 1.0157x over previous
//
#include <hip/hip_runtime.h>
#include <math.h>

#define T_LEN 1024
#define B_SZ  256
#define I_SZ  128
#define H_SZ  64
#define G_SZ  256   // 4*H
#define SUB   32    // recurrence steps per LDS-staged XG sub-chunk

typedef float f32x8 __attribute__((ext_vector_type(8)));
typedef float f32x2 __attribute__((ext_vector_type(2)));

__device__ __forceinline__ float fast_tanh(float x) {   // safe for any |x|
    float e = __expf(-2.0f * fabsf(x));
    float r = (1.0f - e) * __builtin_amdgcn_rcpf(1.0f + e);
    return copysignf(r, x);
}

#define LD8PIN(V, P)                                                        \
    {   float4 t0_ = *reinterpret_cast<const float4*>(P);                   \
        float4 t1_ = *reinterpret_cast<const float4*>((P) + 4);             \
        V = (f32x8){t0_.x, t0_.y, t0_.z, t0_.w, t1_.x, t1_.y, t1_.z, t1_.w};\
        asm volatile("" : "+v"(V)); }

// acc(4 chains) += h[K..K+15]*{VA,VB}; h via v_readlane with LITERAL indices
// (R12 lesson: divergent lane index = UB). 16 readlanes hoisted before FMAs.
#define RL16(VA, VB, K)                                                     \
    {   unsigned s0_  = __builtin_amdgcn_readlane(hu, (K) + 0);             \
        unsigned s1_  = __builtin_amdgcn_readlane(hu, (K) + 1);             \
        unsigned s2_  = __builtin_amdgcn_readlane(hu, (K) + 2);             \
        unsigned s3_  = __builtin_amdgcn_readlane(hu, (K) + 3);             \
        unsigned s4_  = __builtin_amdgcn_readlane(hu, (K) + 4);             \
        unsigned s5_  = __builtin_amdgcn_readlane(hu, (K) + 5);             \
        unsigned s6_  = __builtin_amdgcn_readlane(hu, (K) + 6);             \
        unsigned s7_  = __builtin_amdgcn_readlane(hu, (K) + 7);             \
        unsigned s8_  = __builtin_amdgcn_readlane(hu, (K) + 8);             \
        unsigned s9_  = __builtin_amdgcn_readlane(hu, (K) + 9);             \
        unsigned s10_ = __builtin_amdgcn_readlane(hu, (K) + 10);            \
        unsigned s11_ = __builtin_amdgcn_readlane(hu, (K) + 11);            \
        unsigned s12_ = __builtin_amdgcn_readlane(hu, (K) + 12);            \
        unsigned s13_ = __builtin_amdgcn_readlane(hu, (K) + 13);            \
        unsigned s14_ = __builtin_amdgcn_readlane(hu, (K) + 14);            \
        unsigned s15_ = __builtin_amdgcn_readlane(hu, (K) + 15);            \
        a0 = fmaf(__uint_as_float(s0_),  VA[0], a0);                        \
        a1 = fmaf(__uint_as_float(s1_),  VA[1], a1);                        \
        a2 = fmaf(__uint_as_float(s2_),  VA[2], a2);                        \
        a3 = fmaf(__uint_as_float(s3_),  VA[3], a3);                        \
        a0 = fmaf(__uint_as_float(s4_),  VA[4], a0);                        \
        a1 = fmaf(__uint_as_float(s5_),  VA[5], a1);                        \
        a2 = fmaf(__uint_as_float(s6_),  VA[6], a2);                        \
        a3 = fmaf(__uint_as_float(s7_),  VA[7], a3);                        \
        a0 = fmaf(__uint_as_float(s8_),  VB[0], a0);                        \
        a1 = fmaf(__uint_as_float(s9_),  VB[1], a1);                        \
        a2 = fmaf(__uint_as_float(s10_), VB[2], a2);                        \
        a3 = fmaf(__uint_as_float(s11_), VB[3], a3);                        \
        a0 = fmaf(__uint_as_float(s12_), VB[4], a0);                        \
        a1 = fmaf(__uint_as_float(s13_), VB[5], a1);                        \
        a2 = fmaf(__uint_as_float(s14_), VB[6], a2);                        \
        a3 = fmaf(__uint_as_float(s15_), VB[7], a3); }

// LDS column swizzle for the GEMM tiles
__device__ __forceinline__ int swz(int c) { return c + 4 * (c >> 5); }

// GEMM staging: global -> regs (issued early, latency hidden under compute)
#define GLOAD(K0)                                                           \
    { _Pragma("unroll") for (int i_ = 0; i_ < 4; ++i_) {                    \
        const int mr_ = srow + 32 * i_;                                     \
        pa[i_] = *reinterpret_cast<const float4*>(                          \
            &xch[(size_t)(mt * 128 + mr_) * I_SZ + (K0) + skk]);            \
        pb[i_] = *reinterpret_cast<const float4*>(                          \
            &W_ih[(size_t)(nt * 128 + mr_) * I_SZ + (K0) + skk]); } }

// GEMM staging: regs -> LDS (after compute; one barrier per stage)
#define SWRITE(BUF)                                                         \
    { _Pragma("unroll") for (int i_ = 0; i_ < 4; ++i_) {                    \
        const int mr_ = srow + 32 * i_; const int sm_ = swz(mr_);           \
        as[BUF][skk + 0][sm_] = pa[i_].x; as[BUF][skk + 1][sm_] = pa[i_].y; \
        as[BUF][skk + 2][sm_] = pa[i_].z; as[BUF][skk + 3][sm_] = pa[i_].w; \
        bs[BUF][skk + 0][sm_] = pb[i_].x; bs[BUF][skk + 1][sm_] = pb[i_].y; \
        bs[BUF][skk + 2][sm_] = pb[i_].z; bs[BUF][skk + 3][sm_] = pb[i_].w; } }

// ---------------------------------------------------------------------------
// XG GEMM, double-buffered + f32x2 packed accumulate (R18-proven, ~190us).
// ---------------------------------------------------------------------------
__global__ __launch_bounds__(256, 2) void xg_gemm(
    const float* __restrict__ xch,    // [Mc,128] chunk of x
    const float* __restrict__ W_ih,   // [256,128]
    const float* __restrict__ bias,   // [256]
    float* __restrict__ XG)           // [Mc,256]
{
    const int tid = threadIdx.x;
    const int tx  = tid & 15;
    const int ty  = tid >> 4;
    const int mt  = blockIdx.x;
    const int nt  = blockIdx.y;

    __shared__ __align__(16) float as[2][32][140];   // 35.8 KB
    __shared__ __align__(16) float bs[2][32][140];   // 35.8 KB

    const int n0 = nt * 128 + tx * 8;
    float4 bia = *reinterpret_cast<const float4*>(&bias[n0]);
    float4 bib = *reinterpret_cast<const float4*>(&bias[n0 + 4]);

    f32x2 acc2[8][4];
#pragma unroll
    for (int r = 0; r < 8; ++r)
#pragma unroll
        for (int cc = 0; cc < 4; ++cc) acc2[r][cc] = (f32x2){0.0f, 0.0f};

    const int srow = tid >> 3;            // 0..31
    const int skk  = (tid & 7) * 4;       // 0,4,..,28

    float4 pa[4], pb[4];
    GLOAD(0) SWRITE(0)
    __syncthreads();

#pragma unroll
    for (int ks = 0; ks < 4; ++ks) {
        if (ks < 3) GLOAD((ks + 1) * 32)  // prefetch next stage (in flight)

        const int buf = ks & 1;
#pragma unroll 8
        for (int kk = 0; kk < 32; ++kk) {
            const float4 a0 = *reinterpret_cast<const float4*>(&as[buf][kk][swz(ty * 8)]);
            const float4 a1 = *reinterpret_cast<const float4*>(&as[buf][kk][swz(ty * 8) + 4]);
            const float4 b0 = *reinterpret_cast<const float4*>(&bs[buf][kk][swz(tx * 8)]);
            const float4 b1 = *reinterpret_cast<const float4*>(&bs[buf][kk][swz(tx * 8) + 4]);
            const float av[8] = {a0.x, a0.y, a0.z, a0.w, a1.x, a1.y, a1.z, a1.w};
            const f32x2 bv2[4] = {{b0.x, b0.y}, {b0.z, b0.w},
                                  {b1.x, b1.y}, {b1.z, b1.w}};
#pragma unroll
            for (int r = 0; r < 8; ++r) {
                const f32x2 a2 = {av[r], av[r]};
#pragma unroll
                for (int cc = 0; cc < 4; ++cc)
                    acc2[r][cc] = a2 * bv2[cc] + acc2[r][cc];  // v_pk_fma_f32
            }
        }

        if (ks < 3) {
            SWRITE(buf ^ 1)               // prev readers of buf^1 done (bar ks-1)
            __syncthreads();              // one barrier per stage
        }
    }

#pragma unroll
    for (int r = 0; r < 8; ++r) {
        const size_t m = (size_t)(mt * 128 + ty * 8 + r);
        float4 o0 = {acc2[r][0].x + bia.x, acc2[r][0].y + bia.y,
                     acc2[r][1].x + bia.z, acc2[r][1].y + bia.w};
        float4 o1 = {acc2[r][2].x + bib.x, acc2[r][2].y + bib.y,
                     acc2[r][3].x + bib.z, acc2[r][3].y + bib.w};
        *reinterpret_cast<float4*>(&XG[m * G_SZ + n0])     = o0;
        *reinterpret_cast<float4*>(&XG[m * G_SZ + n0 + 4]) = o1;
    }
}

// ---------------------------------------------------------------------------
// Recurrence (R15/R18 structure — proven 404us, absmax 1.9e-6, VGPR 88).
// 256 threads (4 waves, wave = gate). Lane l of wave g owns full gate row
// g*64+l: 64 W_hh floats pinned (the empirically-proven RA residency limit).
// h/c REPLICATED per wave in lane registers (lane l = unit l). h-dot via
// v_readlane (literal indices) -> SGPR folds into v_fma: zero LDS for h.
// ---------------------------------------------------------------------------
__global__ __launch_bounds__(256, 1) void lstm_rec(
    const float* __restrict__ XG,     // [TC,B,256]
    const float* __restrict__ W_hh,   // [256,64]
    float* __restrict__ h_state,      // [B,64]
    float* __restrict__ c_state,      // [B,64]
    int TC, int first)
{
    const int b = blockIdx.x;
    const int t = threadIdx.x;
    const int l = t & 63;             // lane = unit (cell phase)
    const int g = t >> 6;             // wave = gate: 0=i 1=f 2=g 3=o
    const int row = t;                // gate row g*64+l

    __shared__ __align__(16) float xgl[2][SUB][G_SZ];   // 64 KB
    __shared__ float gs[2][G_SZ];                       // double-buffered gates

    // full W_hh row -> 64 pinned register floats (R8-proven resident)
    const float* ur = W_hh + row * H_SZ;
    f32x8 w0, w1, w2, w3, w4, w5, w6, w7;
    LD8PIN(w0, ur)      LD8PIN(w1, ur +  8) LD8PIN(w2, ur + 16) LD8PIN(w3, ur + 24)
    LD8PIN(w4, ur + 32) LD8PIN(w5, ur + 40) LD8PIN(w6, ur + 48) LD8PIN(w7, ur + 56)

    // replicated state in lane registers (every wave: lane l = unit l)
    float h = first ? 0.0f : h_state[b * H_SZ + l];
    float c = first ? 0.0f : c_state[b * H_SZ + l];

    // stage sub-chunk 0: flat coalesced copy (thread t copies f4 #t+256i)
    {
        float* xf = &xgl[0][0][0];
#pragma unroll
        for (int i = 0; i < 8; ++i) {
            const int F = t + 256 * i;            // float4 index 0..2047
            const int r = F >> 6, cw = F & 63;    // step row, float4 col
            *reinterpret_cast<float4*>(xf + 4 * F) =
                *reinterpret_cast<const float4*>(
                    XG + ((size_t)r * B_SZ + b) * G_SZ + 4 * cw);
        }
    }
    __syncthreads();

    const bool isg = (g == 2);        // wave-uniform
    const int nsub = TC / SUB;
    int db = 0;

    for (int sub = 0; sub < nsub; ++sub) {
        const int cur = sub & 1;
        if (sub + 1 < nsub) {         // stage next sub-chunk (flat copy)
            float* xf = &xgl[cur ^ 1][0][0];
#pragma unroll
            for (int i = 0; i < 8; ++i) {
                const int F = t + 256 * i;
                const int r = (F >> 6) + (sub + 1) * SUB, cw = F & 63;
                *reinterpret_cast<float4*>(xf + 4 * F) =
                    *reinterpret_cast<const float4*>(
                        XG + ((size_t)r * B_SZ + b) * G_SZ + 4 * cw);
            }
        }

#pragma unroll 4
        for (int ts = 0; ts < SUB; ++ts) {
            // h-dot: 64 readlane + 64 FMA (VALU only), hoisted by 16s
            const unsigned hu = __float_as_uint(h);
            float a0 = xgl[cur][ts][row];         // xg seed (banks 0..31, free)
            float a1 = 0.0f, a2 = 0.0f, a3 = 0.0f;
            RL16(w0, w1,  0) RL16(w2, w3, 16)
            RL16(w4, w5, 32) RL16(w6, w7, 48)
            const float acc = (a0 + a1) + (a2 + a3);

            // activation (wave-uniform gate; branchless select)
            const float arg = isg ? (-2.0f * acc) : (-acc);
            const float e = __expf(arg);
            const float r = __builtin_amdgcn_rcpf(1.0f + e);
            const float a = isg ? (1.0f - e) * r : r;

            gs[db][row] = a;                      // banks 0..31, conflict-free
            __syncthreads();                      // gates visible

            // replicated cell update: lane l handles unit l (4 free b32 reads)
            const float ig = gs[db][l];
            const float fg = gs[db][H_SZ + l];
            const float gg = gs[db][2 * H_SZ + l];
            const float og = gs[db][3 * H_SZ + l];
            c = fmaf(fg, c, ig * gg);
            h = og * fast_tanh(c);                // stays in registers
            db ^= 1;
        }
    }

    if (t < H_SZ) {                               // wave 0 writes final state
        h_state[b * H_SZ + t] = h;
        c_state[b * H_SZ + t] = c;
    }
}

// ---------------------------------------------------------------------------
// Reverse single cell (zero init state; W_hh_r drops out) + MLP head.
// ---------------------------------------------------------------------------
__global__ __launch_bounds__(256, 1) void lstm_tail(
    const float* __restrict__ x_last,  // [B,I]
    const float* __restrict__ W_ih_r,  // [256,128]
    const float* __restrict__ b_r,     // [256]
    const float* __restrict__ h_fwd,   // [B,64]
    const float* __restrict__ fc1_w,   // [64,128]
    const float* __restrict__ fc1_b,   // [64]
    const float* __restrict__ fc2_w,   // [32,64]
    const float* __restrict__ fc2_b,   // [32]
    const float* __restrict__ fc3_w,   // [10,32]
    const float* __restrict__ fc3_b,   // [10]
    float* __restrict__ out)           // [B,10]
{
    const int b = blockIdx.x;
    const int j = threadIdx.x;

    __shared__ float xs[I_SZ];
    __shared__ float gs[G_SZ];
    __shared__ float hc[2 * H_SZ];
    __shared__ float h1[64];
    __shared__ float h2[32];

    if (j < I_SZ) xs[j] = x_last[(size_t)b * I_SZ + j];
    if (j < H_SZ) hc[j] = h_fwd[b * H_SZ + j];
    __syncthreads();

    float a0 = b_r[j], a1 = 0.0f, a2 = 0.0f, a3 = 0.0f;
    const float* wrow = W_ih_r + j * I_SZ;
#pragma unroll
    for (int kk = 0; kk < I_SZ; kk += 4) {
        float4 wv = *reinterpret_cast<const float4*>(wrow + kk);
        a0 = fmaf(xs[kk + 0], wv.x, a0);
        a1 = fmaf(xs[kk + 1], wv.y, a1);
        a2 = fmaf(xs[kk + 2], wv.z, a2);
        a3 = fmaf(xs[kk + 3], wv.w, a3);
    }
    const float acc = (a0 + a1) + (a2 + a3);
    const int gate = j >> 6;
    gs[j] = (gate == 2) ? tanhf(acc) : 1.0f / (1.0f + expf(-acc));
    __syncthreads();

    if (j < H_SZ) {
        const float cc = gs[j] * gs[2 * H_SZ + j];     // i*g (c0 = 0)
        hc[H_SZ + j] = gs[3 * H_SZ + j] * tanhf(cc);
    }
    __syncthreads();

    if (j < 64) {
        float s0 = fc1_b[j], s1 = 0.0f, s2 = 0.0f, s3 = 0.0f;
        const float* w = fc1_w + j * 128;
#pragma unroll
        for (int kk = 0; kk < 128; kk += 4) {
            float4 wv = *reinterpret_cast<const float4*>(w + kk);
            s0 = fmaf(hc[kk + 0], wv.x, s0);
            s1 = fmaf(hc[kk + 1], wv.y, s1);
            s2 = fmaf(hc[kk + 2], wv.z, s2);
            s3 = fmaf(hc[kk + 3], wv.w, s3);
        }
        h1[j] = fmaxf((s0 + s1) + (s2 + s3), 0.0f);
    }
    __syncthreads();

    if (j < 32) {
        float s0 = fc2_b[j], s1 = 0.0f, s2 = 0.0f, s3 = 0.0f;
        const float* w = fc2_w + j * 64;
#pragma unroll
        for (int kk = 0; kk < 64; kk += 4) {
            float4 wv = *reinterpret_cast<const float4*>(w + kk);
            s0 = fmaf(h1[kk + 0], wv.x, s0);
            s1 = fmaf(h1[kk + 1], wv.y, s1);
            s2 = fmaf(h1[kk + 2], wv.z, s2);
            s3 = fmaf(h1[kk + 3], wv.w, s3);
        }
        h2[j] = fmaxf((s0 + s1) + (s2 + s3), 0.0f);
    }
    __syncthreads();

    if (j < 10) {
        float s = fc3_b[j];
#pragma unroll
        for (int kk = 0; kk < 32; ++kk) s = fmaf(h2[kk], fc3_w[j * 32 + kk], s);
        out[b * 10 + j] = s;
    }
}

extern "C" void kernel_launch(void* const* d_in, const int* in_sizes, int n_in,
                              void* d_out, int out_size, void* d_ws, size_t ws_size,
                              hipStream_t stream) {
    const float* x      = (const float*)d_in[0];
    const float* W_ih_f = (const float*)d_in[1];
    const float* W_hh_f = (const float*)d_in[2];
    const float* b_f    = (const float*)d_in[3];
    const float* W_ih_r = (const float*)d_in[4];
    // d_in[5] = W_hh_r : unused (zero initial state in reverse single step)
    const float* b_r    = (const float*)d_in[6];
    const float* fc1_w  = (const float*)d_in[7];
    const float* fc1_b  = (const float*)d_in[8];
    const float* fc2_w  = (const float*)d_in[9];
    const float* fc2_b  = (const float*)d_in[10];
    const float* fc3_w  = (const float*)d_in[11];
    const float* fc3_b  = (const float*)d_in[12];
    float* out = (float*)d_out;

    // time-chunk size: largest TC whose XG buffer (+state) fits in ws
    int TC = 1024;
    while (TC > 64 &&
           (size_t)TC * B_SZ * G_SZ * 4 + 2 * B_SZ * H_SZ * 4 > ws_size)
        TC >>= 1;

    float* XG      = (float*)d_ws;
    float* h_state = (float*)((char*)d_ws + (size_t)TC * B_SZ * G_SZ * 4);
    float* c_state = h_state + B_SZ * H_SZ;

    const int NCH = T_LEN / TC;
    for (int ch = 0; ch < NCH; ++ch) {
        const float* xch = x + (size_t)ch * TC * B_SZ * I_SZ;
        hipLaunchKernelGGL(xg_gemm, dim3(TC * B_SZ / 128, 2), dim3(256), 0,
                           stream, xch, W_ih_f, b_f, XG);
        hipLaunchKernelGGL(lstm_rec, dim3(B_SZ), dim3(256), 0, stream,
                           XG, W_hh_f, h_state, c_state, TC, ch == 0 ? 1 : 0);
    }

    const float* x_last = x + (size_t)(T_LEN - 1) * B_SZ * I_SZ;
    hipLaunchKernelGGL(lstm_tail, dim3(B_SZ), dim3(256), 0, stream,
                       x_last, W_ih_r, b_r, h_state,
                       fc1_w, fc1_b, fc2_w, fc2_b, fc3_w, fc3_b, out);
}